// Round 1
// 1285.860 us; speedup vs baseline: 1.2884x; 1.2884x over previous
//
#include <hip/hip_runtime.h>
#include <stdint.h>

#define NE    33554432   // 16384*32*64  elements of each (B,W,64) tensor
#define MROWS 524288     // B*W rows of the cat matrix

typedef __attribute__((ext_vector_type(8))) short short8;
typedef __attribute__((ext_vector_type(4))) float f32x4;
typedef unsigned short ushort_t;
typedef unsigned char uchar_t;

// ---------- helpers ----------
__device__ __forceinline__ unsigned fenc(float f){
  unsigned u=__float_as_uint(f); return (u&0x80000000u)?~u:(u|0x80000000u);
}
__device__ __forceinline__ float fdec(unsigned u){
  return __uint_as_float((u&0x80000000u)?(u&0x7fffffffu):~u);
}
__device__ __forceinline__ void obs(float mn,float mx,float&s,float&zp){
  mn=fminf(mn,0.f); mx=fmaxf(mx,0.f);
  s=fmaxf((mx-mn)/255.0f,1e-8f);
  zp=fminf(fmaxf(rintf(-128.0f-mn/s),-128.f),127.f);
}
__device__ __forceinline__ float qof(float x,float s,float zp){   // quantized code (as float)
  return fminf(fmaxf(rintf(x/s)+zp,-128.f),127.f);
}
__device__ __forceinline__ float fqv(float x,float s,float zp){   // dequantized value
  return (qof(x,s,zp)-zp)*s;
}
__device__ __forceinline__ void wred(float&mn,float&mx){
  #pragma unroll
  for(int o=32;o;o>>=1){mn=fminf(mn,__shfl_xor(mn,o));mx=fmaxf(mx,__shfl_xor(mx,o));}
}

// U layout (uint minmax slots, order-preserving encoded):
// 0,1 x | 2,3 h | 4,5 c | 6..13 gates(i,f,o,cg) | 14,15 fc | 16,17 ic | 18,19 cn | 20,21 hn
// S layout (float):
// 0-5 sx,zx,sh,zh,sc,zc | 6,7 scat,zcat | 8-15 sW[g],zW[g] | 16-23 sG1[g],zG1[g]
// 24-31 sA2[g],zA2[g] | 32-35 sfc,zfc,sic,zic | 36,37 scn,zcn | 38,39 sct,zct | 40,41 shn,zhn
// LUTa[g*256+t] : activation value for biased gate code t (gates i,f,o,cg)
// LUTct[t]      : fq(hardtanh(c_next)) value for biased c_next code t

__global__ void k0_init(unsigned* U){
  int t=threadIdx.x;
  if(t<11){U[2*t]=0xFFFFFFFFu;U[2*t+1]=0u;}
}

__global__ __launch_bounds__(256) void k1_minmax(const float* __restrict__ x,
    const float* __restrict__ h,const float* __restrict__ c,unsigned* U){
  __shared__ float red[8];
  int t=blockIdx.x*256+threadIdx.x, stride=gridDim.x*256;
  int w=threadIdx.x>>6,l=threadIdx.x&63;
  const float4* ps[3]={(const float4*)x,(const float4*)h,(const float4*)c};
  for(int q=0;q<3;q++){
    float mn=3.4e38f,mx=-3.4e38f;
    const float4* p=ps[q];
    for(int e=t;e<NE/4;e+=stride){
      float4 v=p[e];
      mn=fminf(mn,fminf(fminf(v.x,v.y),fminf(v.z,v.w)));
      mx=fmaxf(mx,fmaxf(fmaxf(v.x,v.y),fmaxf(v.z,v.w)));
    }
    wred(mn,mx);
    if(l==0){red[w]=mn;red[4+w]=mx;}
    __syncthreads();
    if(threadIdx.x==0){
      float bmn=fminf(fminf(red[0],red[1]),fminf(red[2],red[3]));
      float bmx=fmaxf(fmaxf(red[4],red[5]),fmaxf(red[6],red[7]));
      atomicMin(&U[2*q],fenc(bmn)); atomicMax(&U[2*q+1],fenc(bmx));
    }
    __syncthreads();
  }
}

// scalars for x/h/c/cat + per-gate weight/bias quantization (single block)
__global__ __launch_bounds__(256) void k2_prep(const float* Wi,const float* bi,
    const float* Wf,const float* bfv,const float* Wo,const float* bo,
    const float* Wcg,const float* bcg,
    const unsigned* U,float* S,ushort_t* Wc,float* bq){
  __shared__ float smn[256],smx[256],sP[4];
  int t=threadIdx.x;
  if(t==0){
    float xmn=fdec(U[0]),xmx=fdec(U[1]),hmn=fdec(U[2]),hmx=fdec(U[3]),cmn=fdec(U[4]),cmx=fdec(U[5]);
    float sx,zx,sh,zh,sc,zc;
    obs(xmn,xmx,sx,zx);obs(hmn,hmx,sh,zh);obs(cmn,cmx,sc,zc);
    S[0]=sx;S[1]=zx;S[2]=sh;S[3]=zh;S[4]=sc;S[5]=zc;
    float cmn2=fminf(fqv(xmn,sx,zx),fqv(hmn,sh,zh));
    float cmx2=fmaxf(fqv(xmx,sx,zx),fqv(hmx,sh,zh));
    float scat,zcat;obs(cmn2,cmx2,scat,zcat);S[6]=scat;S[7]=zcat;
  }
  const float* Wp[4]={Wi,Wf,Wo,Wcg};
  const float* bp[4]={bi,bfv,bo,bcg};
  for(int g=0;g<4;g++){
    float mn=3.4e38f,mx=-3.4e38f;
    for(int i=t;i<8192;i+=256){float v=Wp[g][i];mn=fminf(mn,v);mx=fmaxf(mx,v);}
    smn[t]=mn;smx[t]=mx;__syncthreads();
    for(int ss=128;ss;ss>>=1){
      if(t<ss){smn[t]=fminf(smn[t],smn[t+ss]);smx[t]=fmaxf(smx[t],smx[t+ss]);}
      __syncthreads();
    }
    if(t==0){
      float s_,z_;obs(smn[0],smx[0],s_,z_);
      S[8+2*g]=s_;S[9+2*g]=z_;sP[0]=s_;sP[1]=z_;
      float bmn=3.4e38f,bmx=-3.4e38f;
      for(int i=0;i<64;i++){float v=bp[g][i];bmn=fminf(bmn,v);bmx=fmaxf(bmx,v);}
      float sb,zb;obs(bmn,bmx,sb,zb);sP[2]=sb;sP[3]=zb;
    }
    __syncthreads();
    float s_=sP[0],z_=sP[1],sb=sP[2],zb=sP[3];
    for(int i=t;i<8192;i+=256){
      float cv=qof(Wp[g][i],s_,z_)-z_;                 // centered integer, exact in bf16
      Wc[g*8192+i]=(ushort_t)(__float_as_uint(cv)>>16);
    }
    if(t<64) bq[g*64+t]=fqv(bp[g][t],sb,zb);
    __syncthreads();
  }
}

// quantize: cat -> centered bf16 (in d_out h-half as scratch), c -> biased int8 codes
__global__ __launch_bounds__(256) void k3_quant(const float* __restrict__ x,
    const float* __restrict__ h,const float* __restrict__ c,
    const float* __restrict__ S,ushort_t* __restrict__ catc,uchar_t* __restrict__ qc){
  float sx=S[0],zx=S[1],sh=S[2],zh=S[3],sc=S[4],zc=S[5],scat=S[6],zcat=S[7];
  int t=blockIdx.x*256+threadIdx.x, stride=gridDim.x*256;
  const float4* xp=(const float4*)x; const float4* hp=(const float4*)h;
  for(int e=t;e<MROWS*32;e+=stride){      // 32 float4 per 128-wide row
    int row=e>>5,k4=e&31;
    float4 v; float s1,z1;
    if(k4<16){v=xp[row*16+k4];s1=sx;z1=zx;}
    else     {v=hp[row*16+(k4-16)];s1=sh;z1=zh;}
    float c0=qof((qof(v.x,s1,z1)-z1)*s1,scat,zcat)-zcat;
    float c1=qof((qof(v.y,s1,z1)-z1)*s1,scat,zcat)-zcat;
    float c2=qof((qof(v.z,s1,z1)-z1)*s1,scat,zcat)-zcat;
    float c3=qof((qof(v.w,s1,z1)-z1)*s1,scat,zcat)-zcat;
    uint2 o;
    o.x=(__float_as_uint(c0)>>16)|((__float_as_uint(c1)>>16)<<16);
    o.y=(__float_as_uint(c2)>>16)|((__float_as_uint(c3)>>16)<<16);
    ((uint2*)catc)[e]=o;
  }
  const float4* cp=(const float4*)c;
  unsigned* qcp=(unsigned*)qc;
  for(int e=t;e<NE/4;e+=stride){
    float4 v=cp[e];
    int q0=(int)qof(v.x,sc,zc)+128,q1=(int)qof(v.y,sc,zc)+128;
    int q2=(int)qof(v.z,sc,zc)+128,q3=(int)qof(v.w,sc,zc)+128;
    qcp[e]=(unsigned)q0|((unsigned)q1<<8)|((unsigned)q2<<16)|((unsigned)q3<<24);
  }
}

// GEMM pass A: exact integer GEMM, gate pre-act minmax only (no LDS roundtrip)
__global__ __launch_bounds__(256) void g0_minmax(const ushort_t* __restrict__ catc,
    const ushort_t* __restrict__ Wc,const float* __restrict__ S,
    const float* __restrict__ bq,unsigned* U){
  int tid=threadIdx.x,w=tid>>6,l=tid&63,l15=l&15,lq=l>>4;
  float sgp=S[6]*S[8+2*w];                   // s_cat * s_w[gate]
  short8 bf[4][4];
  #pragma unroll
  for(int nt=0;nt<4;nt++)
    #pragma unroll
    for(int ks=0;ks<4;ks++)
      bf[nt][ks]=*(const short8*)(Wc+w*8192+(nt*16+l15)*128+ks*32+lq*8);
  float bqr[4];
  #pragma unroll
  for(int nt=0;nt<4;nt++) bqr[nt]=bq[w*64+nt*16+l15];
  float mn=3.4e38f,mx=-3.4e38f;
  for(int gi=0;gi<8;gi++){
    int rowbase=(blockIdx.x*8+gi)*64;
    #pragma unroll
    for(int mt=0;mt<4;mt++){
      const ushort_t* arow=catc+(size_t)(rowbase+mt*16+l15)*128;
      short8 af[4];
      #pragma unroll
      for(int ks=0;ks<4;ks++) af[ks]=*(const short8*)(arow+ks*32+lq*8);
      f32x4 acc[4];
      #pragma unroll
      for(int nt=0;nt<4;nt++) acc[nt]=(f32x4){0.f,0.f,0.f,0.f};
      #pragma unroll
      for(int ks=0;ks<4;ks++)
        #pragma unroll
        for(int nt=0;nt<4;nt++)
          acc[nt]=__builtin_amdgcn_mfma_f32_16x16x32_bf16(af[ks],bf[nt][ks],acc[nt],0,0,0);
      #pragma unroll
      for(int nt=0;nt<4;nt++)
        #pragma unroll
        for(int r=0;r<4;r++){
          float v=sgp*acc[nt][r]+bqr[nt];
          mn=fminf(mn,v);mx=fmaxf(mx,v);
        }
    }
  }
  wred(mn,mx);
  if(l==0){atomicMin(&U[6+2*w],fenc(mn));atomicMax(&U[7+2*w],fenc(mx));}
}

// GEMM pass B: quantize pre-acts to codes ONCE, store packed codes,
// fc/ic minmax via activation LUT. This is the last GEMM pass.
__global__ __launch_bounds__(256,2) void g1_codes(const ushort_t* __restrict__ catc,
    const ushort_t* __restrict__ Wc,const float* __restrict__ S,
    const float* __restrict__ bq,const uchar_t* __restrict__ qc,
    const float* __restrict__ LUTa,unsigned* U,
    unsigned* __restrict__ qpack,uchar_t* __restrict__ qo){
  __shared__ float ldsq[4][64][64];   // gate codes as floats
  __shared__ float lut[1024];
  __shared__ float red[16];
  int tid=threadIdx.x,w=tid>>6,l=tid&63,l15=l&15,lq=l>>4;
  for(int i=tid;i<1024;i+=256) lut[i]=LUTa[i];
  float sgp=S[6]*S[8+2*w];
  float sg1=S[16+2*w],zg1=S[17+2*w];
  float sc=S[4],zc128=S[5]+128.0f;
  short8 bf[4][4];
  #pragma unroll
  for(int nt=0;nt<4;nt++)
    #pragma unroll
    for(int ks=0;ks<4;ks++)
      bf[nt][ks]=*(const short8*)(Wc+w*8192+(nt*16+l15)*128+ks*32+lq*8);
  float bqr[4];
  #pragma unroll
  for(int nt=0;nt<4;nt++) bqr[nt]=bq[w*64+nt*16+l15];
  float fmn=3.4e38f,fmx=-3.4e38f,imn=3.4e38f,imx=-3.4e38f;
  for(int gi=0;gi<8;gi++){
    int grp=blockIdx.x*8+gi;
    int rowbase=grp*64;
    #pragma unroll
    for(int mt=0;mt<4;mt++){
      const ushort_t* arow=catc+(size_t)(rowbase+mt*16+l15)*128;
      short8 af[4];
      #pragma unroll
      for(int ks=0;ks<4;ks++) af[ks]=*(const short8*)(arow+ks*32+lq*8);
      f32x4 acc[4];
      #pragma unroll
      for(int nt=0;nt<4;nt++) acc[nt]=(f32x4){0.f,0.f,0.f,0.f};
      #pragma unroll
      for(int ks=0;ks<4;ks++)
        #pragma unroll
        for(int nt=0;nt<4;nt++)
          acc[nt]=__builtin_amdgcn_mfma_f32_16x16x32_bf16(af[ks],bf[nt][ks],acc[nt],0,0,0);
      #pragma unroll
      for(int nt=0;nt<4;nt++)
        #pragma unroll
        for(int r=0;r<4;r++){
          float v=sgp*acc[nt][r]+bqr[nt];
          ldsq[w][mt*16+lq*4+r][nt*16+l15]=qof(v,sg1,zg1);   // the only per-elem divide
        }
    }
    __syncthreads();
    #pragma unroll
    for(int i=0;i<16;i++){
      int e=tid+256*i;
      int row=e>>6,col=e&63;
      int gidx=grp*4096+e;
      int q0=(int)ldsq[0][row][col]+128;   // i
      int q1=(int)ldsq[1][row][col]+128;   // f
      int q2=(int)ldsq[2][row][col]+128;   // o
      int q3=(int)ldsq[3][row][col]+128;   // cg
      int qcb=(int)qc[gidx];
      qpack[gidx]=(unsigned)q0|((unsigned)q1<<8)|((unsigned)q3<<16)|((unsigned)qcb<<24);
      qo[gidx]=(uchar_t)q2;
      float avi=lut[q0],avf=lut[256+q1],avcg=lut[768+q3];
      float cv=((float)qcb-zc128)*sc;
      float fc=avf*cv,ic=avi*avcg;
      fmn=fminf(fmn,fc);fmx=fmaxf(fmx,fc);
      imn=fminf(imn,ic);imx=fmaxf(imx,ic);
    }
    __syncthreads();
  }
  wred(fmn,fmx);wred(imn,imx);
  if(l==0){red[w]=fmn;red[4+w]=fmx;red[8+w]=imn;red[12+w]=imx;}
  __syncthreads();
  if(tid==0){
    float a=fminf(fminf(red[0],red[1]),fminf(red[2],red[3]));
    float b=fmaxf(fmaxf(red[4],red[5]),fmaxf(red[6],red[7]));
    atomicMin(&U[14],fenc(a));atomicMax(&U[15],fenc(b));
    a=fminf(fminf(red[8],red[9]),fminf(red[10],red[11]));
    b=fmaxf(fmaxf(red[12],red[13]),fmaxf(red[14],red[15]));
    atomicMin(&U[16],fenc(a));atomicMax(&U[17],fenc(b));
  }
}

// elementwise: cn minmax + store fc/ic codes (replaces GEMM MODE 2)
__global__ __launch_bounds__(256) void e2_cn(const unsigned* __restrict__ qpack,
    const float* __restrict__ S,const float* __restrict__ LUTa,
    unsigned* U,ushort_t* __restrict__ qfcic){
  __shared__ float lut[1024];
  __shared__ float red[8];
  int tid=threadIdx.x;
  for(int i=tid;i<1024;i+=256) lut[i]=LUTa[i];
  float sc=S[4],zc128=S[5]+128.0f;
  float sfc=S[32],zfc=S[33],sic=S[34],zic=S[35];
  __syncthreads();
  float mn=3.4e38f,mx=-3.4e38f;
  int t=blockIdx.x*256+tid,stride=gridDim.x*256;
  for(int e=t;e<NE;e+=stride){
    unsigned u=qpack[e];
    int q0=u&255,q1=(u>>8)&255,q3=(u>>16)&255,qcb=u>>24;
    float avi=lut[q0],avf=lut[256+q1],avcg=lut[768+q3];
    float cv=((float)qcb-zc128)*sc;
    float fc=avf*cv,ic=avi*avcg;
    float qfc=qof(fc,sfc,zfc),qic=qof(ic,sic,zic);
    float cn=(qfc-zfc)*sfc+(qic-zic)*sic;
    mn=fminf(mn,cn);mx=fmaxf(mx,cn);
    qfcic[e]=(ushort_t)(((int)qfc+128)|(((int)qic+128)<<8));
  }
  int w=tid>>6,l=tid&63;
  wred(mn,mx);
  if(l==0){red[w]=mn;red[4+w]=mx;}
  __syncthreads();
  if(tid==0){
    float a=fminf(fminf(red[0],red[1]),fminf(red[2],red[3]));
    float b=fmaxf(fmaxf(red[4],red[5]),fmaxf(red[6],red[7]));
    atomicMin(&U[18],fenc(a));atomicMax(&U[19],fenc(b));
  }
}

// elementwise: c_next codes + h_raw minmax (replaces GEMM MODE 3)
__global__ __launch_bounds__(256) void e3_hmm(const ushort_t* __restrict__ qfcic,
    const uchar_t* __restrict__ qo,const float* __restrict__ S,
    const float* __restrict__ LUTa,const float* __restrict__ LUTct,
    unsigned* U,uchar_t* __restrict__ qcn){
  __shared__ float lao[256],lct[256];
  __shared__ float red[8];
  int tid=threadIdx.x;
  lao[tid]=LUTa[512+tid];lct[tid]=LUTct[tid];
  float sfc=S[32],zfc128=S[33]+128.0f,sic=S[34],zic128=S[35]+128.0f;
  float scn=S[36],zcn=S[37];
  __syncthreads();
  float mn=3.4e38f,mx=-3.4e38f;
  int t=blockIdx.x*256+tid,stride=gridDim.x*256;
  for(int e=t;e<NE;e+=stride){
    int u=qfcic[e];
    float fcv=((float)(u&255)-zfc128)*sfc;
    float icv=((float)(u>>8)-zic128)*sic;
    float cn=fcv+icv;
    float qcf=qof(cn,scn,zcn);
    int qb=(int)qcf+128;
    qcn[e]=(uchar_t)qb;
    float hr=lao[qo[e]]*lct[qb];
    mn=fminf(mn,hr);mx=fmaxf(mx,hr);
  }
  int w=tid>>6,l=tid&63;
  wred(mn,mx);
  if(l==0){red[w]=mn;red[4+w]=mx;}
  __syncthreads();
  if(tid==0){
    float a=fminf(fminf(red[0],red[1]),fminf(red[2],red[3]));
    float b=fmaxf(fmaxf(red[4],red[5]),fmaxf(red[6],red[7]));
    atomicMin(&U[20],fenc(a));atomicMax(&U[21],fenc(b));
  }
}

// scalar stages + LUT builds between reduction passes
__global__ __launch_bounds__(256) void k_post(int stage,const unsigned* U,float* S,
    float* LUTa,float* LUTct){
  __shared__ float sh[16];
  int t=threadIdx.x;
  if(stage==0){
    if(t==0){
      for(int g=0;g<4;g++){
        float mn=fdec(U[6+2*g]),mx=fdec(U[7+2*g]);
        float s1,z1;obs(mn,mx,s1,z1);S[16+2*g]=s1;S[17+2*g]=z1;
        float gmn=fqv(mn,s1,z1),gmx=fqv(mx,s1,z1);
        float amn,amx;
        if(g==3){amn=fminf(fmaxf(gmn,-1.f),1.f);amx=fminf(fmaxf(gmx,-1.f),1.f);}
        else{amn=fminf(fmaxf(gmn/6.0f+0.5f,0.f),1.f);amx=fminf(fmaxf(gmx/6.0f+0.5f,0.f),1.f);}
        float s2,z2;obs(amn,amx,s2,z2);S[24+2*g]=s2;S[25+2*g]=z2;
        sh[4*g]=s1;sh[4*g+1]=z1;sh[4*g+2]=s2;sh[4*g+3]=z2;
      }
    }
    __syncthreads();
    for(int g=0;g<4;g++){
      float s1=sh[4*g],z1=sh[4*g+1],s2=sh[4*g+2],z2=sh[4*g+3];
      float g1=((float)(t-128)-z1)*s1;            // identical to (qof(v)-zg1)*sg1
      float a=(g==3)?fminf(fmaxf(g1,-1.f),1.f):fminf(fmaxf(g1/6.0f+0.5f,0.f),1.f);
      LUTa[g*256+t]=fqv(a,s2,z2);
    }
  } else if(stage==1){
    if(t==0){
      float s,z;
      obs(fdec(U[14]),fdec(U[15]),s,z);S[32]=s;S[33]=z;
      obs(fdec(U[16]),fdec(U[17]),s,z);S[34]=s;S[35]=z;
    }
  } else if(stage==2){
    if(t==0){
      float mn=fdec(U[18]),mx=fdec(U[19]);
      float s,z;obs(mn,mx,s,z);S[36]=s;S[37]=z;
      float tmn=fminf(fmaxf(fqv(mn,s,z),-1.f),1.f);
      float tmx=fminf(fmaxf(fqv(mx,s,z),-1.f),1.f);
      float s2,z2;obs(tmn,tmx,s2,z2);S[38]=s2;S[39]=z2;
      sh[0]=s;sh[1]=z;sh[2]=s2;sh[3]=z2;
    }
    __syncthreads();
    float scn=sh[0],zcn=sh[1],sct=sh[2],zct=sh[3];
    float cnv=((float)(t-128)-zcn)*scn;
    float ct=fminf(fmaxf(cnv,-1.f),1.f);
    LUTct[t]=fqv(ct,sct,zct);
  } else {
    if(t==0){float s,z;obs(fdec(U[20]),fdec(U[21]),s,z);S[40]=s;S[41]=z;}
  }
}

// final outputs: h and c from codes + LUTs
__global__ __launch_bounds__(256) void k9_out(const uchar_t* __restrict__ qo,
    const uchar_t* __restrict__ qcn,const float* __restrict__ S,
    const float* __restrict__ LUTa,const float* __restrict__ LUTct,
    float* __restrict__ hout,float* __restrict__ cout){
  __shared__ float lao[256],lct[256];
  int tid=threadIdx.x;
  lao[tid]=LUTa[512+tid];lct[tid]=LUTct[tid];
  float scn=S[36],zcn128=S[37]+128.0f,shn=S[40],zhn=S[41];
  __syncthreads();
  int t=blockIdx.x*256+tid,stride=gridDim.x*256;
  const unsigned* op=(const unsigned*)qo;
  const unsigned* cp=(const unsigned*)qcn;
  for(int e=t;e<NE/4;e+=stride){
    unsigned uo=op[e],uc=cp[e];
    float4 hv,cv;
    float* ph=&hv.x;float* pc=&cv.x;
    #pragma unroll
    for(int j=0;j<4;j++){
      int qoj=(uo>>(8*j))&255,qcj=(uc>>(8*j))&255;
      float cnv=((float)qcj-zcn128)*scn;
      float hr=lao[qoj]*lct[qcj];
      float qh=qof(hr,shn,zhn);
      ph[j]=(qh-zhn)*shn;
      pc[j]=cnv;
    }
    ((float4*)hout)[e]=hv;
    ((float4*)cout)[e]=cv;
  }
}

extern "C" void kernel_launch(void* const* d_in,const int* in_sizes,int n_in,
                              void* d_out,int out_size,void* d_ws,size_t ws_size,
                              hipStream_t stream){
  (void)in_sizes;(void)n_in;(void)out_size;(void)ws_size;
  const float* x  =(const float*)d_in[0];
  const float* h  =(const float*)d_in[1];
  const float* c  =(const float*)d_in[2];
  const float* Wi =(const float*)d_in[3];  const float* bi =(const float*)d_in[4];
  const float* Wf =(const float*)d_in[5];  const float* bfv=(const float*)d_in[6];
  const float* Wo =(const float*)d_in[7];  const float* bo =(const float*)d_in[8];
  const float* Wcg=(const float*)d_in[9];  const float* bcg=(const float*)d_in[10];

  char* ws=(char*)d_ws;
  unsigned* U =(unsigned*)ws;                 // 128 B
  float* S    =(float*)(ws+128);              // 256 B
  float* bq   =(float*)(ws+512);              // 1 KB
  ushort_t* Wc=(ushort_t*)(ws+2048);          // 64 KB centered-bf16 weights
  float* LUTa =(float*)(ws+69632);            // 4 KB  activation LUT (4 gates x 256)
  float* LUTct=(float*)(ws+73728);            // 1 KB  fq(hardtanh(c_next)) LUT
  uchar_t* qc =(uchar_t*)(ws+(1<<20));        // 32 MB c codes (biased)
  uchar_t* qo =qc +(size_t)NE;                // 32 MB o-gate codes (biased)
  uchar_t* qcn=qo +(size_t)NE;                // 32 MB c_next codes (biased)
  // d_out reuse: h-half = catc scratch (g0/g1), then qfcic (e2/e3), then h_out.
  //              c-half = qpack scratch (g1/e2), then c_out (k9).
  ushort_t* catc=(ushort_t*)d_out;
  unsigned* qpack=(unsigned*)((float*)d_out+NE);
  ushort_t* qfcic=(ushort_t*)d_out;
  float* h_out=(float*)d_out;
  float* c_out=(float*)d_out+NE;

  k0_init<<<1,64,0,stream>>>(U);
  k1_minmax<<<1024,256,0,stream>>>(x,h,c,U);
  k2_prep<<<1,256,0,stream>>>(Wi,bi,Wf,bfv,Wo,bo,Wcg,bcg,U,S,Wc,bq);
  k3_quant<<<2048,256,0,stream>>>(x,h,c,S,catc,qc);
  g0_minmax<<<1024,256,0,stream>>>(catc,Wc,S,bq,U);
  k_post<<<1,256,0,stream>>>(0,U,S,LUTa,LUTct);
  g1_codes<<<1024,256,0,stream>>>(catc,Wc,S,bq,qc,LUTa,U,qpack,qo);
  k_post<<<1,256,0,stream>>>(1,U,S,LUTa,LUTct);
  e2_cn<<<2048,256,0,stream>>>(qpack,S,LUTa,U,qfcic);
  k_post<<<1,256,0,stream>>>(2,U,S,LUTa,LUTct);
  e3_hmm<<<2048,256,0,stream>>>(qfcic,qo,S,LUTa,LUTct,U,qcn);
  k_post<<<1,256,0,stream>>>(3,U,S,LUTa,LUTct);
  k9_out<<<2048,256,0,stream>>>(qo,qcn,S,LUTa,LUTct,h_out,c_out);
}